// Round 1
// 242.717 us; speedup vs baseline: 1.0254x; 1.0254x over previous
//
#include <hip/hip_runtime.h>
#include <cmath>

#define BB 2
#define LL 2048
#define DD 1024
#define HH 16
#define HDD 64

typedef _Float16 v8h __attribute__((ext_vector_type(8)));
typedef _Float16 v4h __attribute__((ext_vector_type(4)));
typedef _Float16 v2h __attribute__((ext_vector_type(2)));
typedef float v4f __attribute__((ext_vector_type(4)));

#define LOG2E 1.44269504089f
#define NEGB  (-1.442695e9f)      /* -1e9 * log2e */

// async global->LDS, 16B per lane.
#define GLD(gp, lp)                                                        \
  __builtin_amdgcn_global_load_lds(                                        \
      (const __attribute__((address_space(1))) void*)(gp),                 \
      (__attribute__((address_space(3))) void*)(lp), 16, 0, 0)

// ---------------------------------------------------------------------------
// fp32 -> f16 conversion: hs + Wq/Wk/Wv (into wqkvh) + Wo.
// ---------------------------------------------------------------------------
__global__ __launch_bounds__(256) void cvt_all(
    const float* __restrict__ hs, const float* __restrict__ wq,
    const float* __restrict__ wk, const float* __restrict__ wv,
    const float* __restrict__ wo, _Float16* __restrict__ hsh,
    _Float16* __restrict__ wqkvh, _Float16* __restrict__ woh)
{
  const int i = blockIdx.x * 256 + threadIdx.x;
  const float* s;
  _Float16* d;
  if (i < 1048576)      { s = hs + (size_t)i * 4;            d = hsh + (size_t)i * 4; }
  else if (i < 1310720) { int j = i - 1048576; s = wq + (size_t)j * 4; d = wqkvh + (size_t)j * 4; }
  else if (i < 1572864) { int j = i - 1310720; s = wk + (size_t)j * 4; d = wqkvh + 1048576 + (size_t)j * 4; }
  else if (i < 1835008) { int j = i - 1572864; s = wv + (size_t)j * 4; d = wqkvh + 2097152 + (size_t)j * 4; }
  else                  { int j = i - 1835008; s = wo + (size_t)j * 4; d = woh + (size_t)j * 4; }
  float4 v = *(const float4*)s;
  v4h o;
  o[0] = (_Float16)v.x; o[1] = (_Float16)v.y;
  o[2] = (_Float16)v.z; o[3] = (_Float16)v.w;
  *(v4h*)d = o;
}

// ---------------------------------------------------------------------------
// cos/sin table from phi: csh2[(b*16+h)*2048 + l] = packed f16 {cos, sin}.
// Also writes aml2[b*2048+l] = am * log2e (attn reads it per-tile from L2).
// ---------------------------------------------------------------------------
__global__ __launch_bounds__(256) void csgen(
    const float* __restrict__ phi, const float* __restrict__ amk,
    unsigned* __restrict__ csh2, float* __restrict__ aml2)
{
  const int o = blockIdx.x * 256 + threadIdx.x;  // 65536 = B*H*L
  if (o < BB * LL) aml2[o] = amk[o] * LOG2E;
  const int l = o & 2047;
  const int h = (o >> 11) & 15;
  const int b = o >> 15;
  const float ph = phi[(b * 2048 + l) * 16 + h];
  v2h cs;
  cs[0] = (_Float16)cosf(ph);
  cs[1] = (_Float16)sinf(ph);
  csh2[o] = __builtin_bit_cast(unsigned, cs);
}

// ---------------------------------------------------------------------------
// m97-style MFMA GEMM core: 128x128 tile, BK=32, 256 thr.
// ---------------------------------------------------------------------------
__device__ __forceinline__ void gemm_loop(
    const _Float16* __restrict__ A, const _Float16* __restrict__ W, const int K,
    const int m0, const int n0, const int tid, const int wave, const int lane,
    _Float16* As, _Float16* Bs, v4f acc[4][4])
{
  const int quad = lane >> 4;
  const int ql = lane & 15;
  const int wm = (wave >> 1) * 64;
  const int wn = (wave & 1) * 64;
  const int srow = tid >> 2;
  const int skof = (tid & 3) * 8;
  const _Float16* Ap = A + (size_t)(m0 + srow) * K + skof;
  const _Float16* Wp = W + (size_t)(n0 + srow) * K + skof;
  const size_t rstep = (size_t)64 * K;
  for (int k0 = 0; k0 < K; k0 += 32) {
    __syncthreads();
    GLD(Ap + k0,         As + tid * 8);
    GLD(Ap + rstep + k0, As + 2048 + tid * 8);
    GLD(Wp + k0,         Bs + tid * 8);
    GLD(Wp + rstep + k0, Bs + 2048 + tid * 8);
    __syncthreads();
    v8h af[4], bf[4];
#pragma unroll
    for (int mt = 0; mt < 4; ++mt)
      af[mt] = *(const v8h*)&As[(wm + mt * 16 + ql) * 32 + quad * 8];
#pragma unroll
    for (int nt = 0; nt < 4; ++nt)
      bf[nt] = *(const v8h*)&Bs[(wn + nt * 16 + ql) * 32 + quad * 8];
#pragma unroll
    for (int mt = 0; mt < 4; ++mt)
#pragma unroll
      for (int nt = 0; nt < 4; ++nt)
        acc[mt][nt] = __builtin_amdgcn_mfma_f32_16x16x32_f16(
            af[mt], bf[nt], acc[mt][nt], 0, 0, 0);
  }
}

// ---------------------------------------------------------------------------
// Fused QKV GEMM. Epilogue:
//   q-band: +bias, rotary (fp32), scale by (1/8)*log2e, single f16 rounding
//   k-band: +bias, rotary (fp32), f16
//   v-band: +bias, written directly in VT2 layout (8B unit [j=key>>2][d])
// ---------------------------------------------------------------------------
__global__ __launch_bounds__(256) void gemm_qkv(
    const _Float16* __restrict__ A, const _Float16* __restrict__ W,
    const float* __restrict__ bqp, const float* __restrict__ bkp,
    const float* __restrict__ bvp, const unsigned* __restrict__ csh2,
    _Float16* __restrict__ qh, _Float16* __restrict__ kh,
    _Float16* __restrict__ vt2)
{
  __shared__ _Float16 As[128 * 32];
  __shared__ _Float16 Bs[128 * 32];
  const int tid = threadIdx.x, lane = tid & 63, wave = tid >> 6;
  const int quad = lane >> 4, ql = lane & 15;
  const int m0 = blockIdx.y * 128, n0 = blockIdx.x * 128;
  v4f acc[4][4];
#pragma unroll
  for (int mt = 0; mt < 4; ++mt)
#pragma unroll
    for (int nt = 0; nt < 4; ++nt) acc[mt][nt] = (v4f){0.f, 0.f, 0.f, 0.f};
  gemm_loop(A, W, DD, m0, n0, tid, wave, lane, As, Bs, acc);

  const int buf = n0 >> 10;                       // 0=q 1=k 2=v
  const int col0 = (n0 & 1023) + (wave & 1) * 64; // 64-col band == one head
  const int hh = col0 >> 6;
  const int mr0 = m0 + (wave >> 1) * 64;

  if (buf == 2) {
    float bb4[4];
#pragma unroll
    for (int nt = 0; nt < 4; ++nt) bb4[nt] = bvp[col0 + nt * 16 + ql];
#pragma unroll
    for (int mt = 0; mt < 4; ++mt) {
      const int row = mr0 + mt * 16 + quad * 4;   // keys row..row+3
      const int b_ = row >> 11;
      const int l = row & 2047;
      _Float16* dst = vt2 + ((size_t)(b_ * 16 + hh) * 32 + (l >> 6)) * 4096 +
                      ((l >> 2) & 15) * 256;
#pragma unroll
      for (int nt = 0; nt < 4; ++nt) {
        const int d = nt * 16 + ql;
        v4h o4;
#pragma unroll
        for (int r = 0; r < 4; ++r) o4[r] = (_Float16)(acc[mt][nt][r] + bb4[nt]);
        *(v4h*)&dst[d * 4] = o4;
      }
    }
  } else {
    const float scl = (buf == 0) ? 0.125f * LOG2E : 1.0f;
    _Float16* outp = (buf == 0) ? qh : kh;
    const float* bias = (buf == 0) ? bqp : bkp;
    float bb4[4];
#pragma unroll
    for (int nt = 0; nt < 4; ++nt) bb4[nt] = bias[col0 + nt * 16 + ql];
#pragma unroll
    for (int mt = 0; mt < 4; ++mt)
#pragma unroll
      for (int r = 0; r < 4; ++r) {
        const int row = mr0 + mt * 16 + quad * 4 + r;
        const int b_ = row >> 11;
        const int l = row & 2047;
        const v2h c2 = __builtin_bit_cast(
            v2h, csh2[(b_ * 16 + hh) * 2048 + l]);
        const float c = (float)c2[0], s = (float)c2[1];
        _Float16* orow = outp + (size_t)row * DD + col0 + ql;
#pragma unroll
        for (int pp = 0; pp < 2; ++pp) {
          const float a0 = acc[mt][pp][r] + bb4[pp];
          const float a1 = acc[mt][pp + 2][r] + bb4[pp + 2];
          orow[pp * 16]        = (_Float16)((a0 * c - a1 * s) * scl);
          orow[(pp + 2) * 16]  = (_Float16)((a1 * c + a0 * s) * scl);
        }
      }
  }
}

// ---------------------------------------------------------------------------
// O-proj GEMM, re-tiled 128(M)x64(N): grid 16x32 = 512 blocks (2/CU instead
// of 1/CU at 128x128) -- the kernel was latency-bound at 1 block/CU.
// Waves: 2x2 over (128M x 64N); per-wave 64x32 -> acc[4][2].
// ---------------------------------------------------------------------------
__global__ __launch_bounds__(256) void gemm_o(
    const _Float16* __restrict__ A, const _Float16* __restrict__ W,
    const float* __restrict__ bo, const float* __restrict__ res,
    float* __restrict__ out)
{
  __shared__ _Float16 As[128 * 32];
  __shared__ _Float16 Bs[64 * 32];
  const int tid = threadIdx.x, lane = tid & 63, wave = tid >> 6;
  const int quad = lane >> 4, ql = lane & 15;
  const int m0 = blockIdx.y * 128, n0 = blockIdx.x * 64;
  v4f acc[4][2];
#pragma unroll
  for (int mt = 0; mt < 4; ++mt)
#pragma unroll
    for (int nt = 0; nt < 2; ++nt) acc[mt][nt] = (v4f){0.f, 0.f, 0.f, 0.f};
  const int wm = (wave >> 1) * 64;
  const int wn = (wave & 1) * 32;
  const int srow = tid >> 2;
  const int skof = (tid & 3) * 8;
  const _Float16* Ap = A + (size_t)(m0 + srow) * DD + skof;
  const _Float16* Wp = W + (size_t)(n0 + srow) * DD + skof;
  const size_t rstep = (size_t)64 * DD;
  for (int k0 = 0; k0 < DD; k0 += 32) {
    __syncthreads();
    GLD(Ap + k0,         As + tid * 8);
    GLD(Ap + rstep + k0, As + 2048 + tid * 8);
    GLD(Wp + k0,         Bs + tid * 8);
    __syncthreads();
    v8h af[4], bf[2];
#pragma unroll
    for (int mt = 0; mt < 4; ++mt)
      af[mt] = *(const v8h*)&As[(wm + mt * 16 + ql) * 32 + quad * 8];
#pragma unroll
    for (int nt = 0; nt < 2; ++nt)
      bf[nt] = *(const v8h*)&Bs[(wn + nt * 16 + ql) * 32 + quad * 8];
#pragma unroll
    for (int mt = 0; mt < 4; ++mt)
#pragma unroll
      for (int nt = 0; nt < 2; ++nt)
        acc[mt][nt] = __builtin_amdgcn_mfma_f32_16x16x32_f16(
            af[mt], bf[nt], acc[mt][nt], 0, 0, 0);
  }
#pragma unroll
  for (int nt = 0; nt < 2; ++nt) {
    const int col = n0 + wn + nt * 16 + ql;
    const float bb = bo[col];
#pragma unroll
    for (int mt = 0; mt < 4; ++mt)
#pragma unroll
      for (int r = 0; r < 4; ++r) {
        const int row = m0 + wm + mt * 16 + quad * 4 + r;
        const size_t ix = (size_t)row * DD + col;
        out[ix] = acc[mt][nt][r] + bb + res[ix];
      }
  }
}

// ---------------------------------------------------------------------------
// Flash attention, no online-max (scores bounded). T3/T4 schedule:
//   K triple-buffered (depth-2 prefetch), V double-buffered; LDS = 40960 B
//   exactly (4 blocks/CU). am*log2e moved from LDS to a global table,
//   prefetched one tile ahead into registers alongside cos/sin.
//   Raw s_barrier with counted s_waitcnt vmcnt(2): the 2 K[t+2] GLDs stay in
//   flight across the barrier (never a full vmcnt(0) drain in steady state).
// Issue order per tile t: cs/am reg loads, V[t+1] GLD x2, K[t+2] GLD x2.
// cs/am are consumed (reg copies) before the counted wait -> exact counting.
// Safety: each wave's ds_reads are consumed by MFMAs (compiler lgkmcnt)
// before the barrier; each wave waits its own staging GLDs before the
// barrier, so post-barrier readers see complete tiles.
// ---------------------------------------------------------------------------
__global__ __launch_bounds__(256, 4) void attn_db(
    const _Float16* __restrict__ Q, const _Float16* __restrict__ K,
    const _Float16* __restrict__ VT2, const unsigned* __restrict__ csh2,
    const float* __restrict__ aml2, _Float16* __restrict__ ctx)
{
  __shared__ _Float16 Kt[3][4096];   // 64 rows x 64 dims (16B-swizzled), 24KB
  __shared__ _Float16 Vt[2][4096];   // VT2 tile image (8B units j-major), 16KB

  const int tid  = threadIdx.x;
  const int lane = tid & 63;
  const int wave = tid >> 6;
  const int quad = lane >> 4;
  const int ql   = lane & 15;
  const int bid  = blockIdx.x;       // 1024 = 32 qt * 32 bh
  const int bh = bid & 31;           // XCD swizzle: same (b,h) -> same XCD
  const int qt = bid >> 5;
  const int h  = bh & 15;
  const int b  = bh >> 4;
  const int q0w = qt * 64 + wave * 16;
  const int qglob = q0w + ql;
  const int csb = bh * LL;

  // Q B-fragment (bias+rotary+log2e/8 pre-folded at GEMM epilogue)
  v8h qf[2];
  {
    const _Float16* qp = Q + ((size_t)(b * LL + qglob)) * DD + h * 64 + quad * 8;
    qf[0] = *(const v8h*)qp;
    qf[1] = *(const v8h*)(qp + 32);
  }
  // {cos_q, sin_q} B-fragment for the mask MFMA
  v4h bq = (v4h){0, 0, 0, 0};
  {
    const v2h c2 = __builtin_bit_cast(v2h, csh2[csb + qglob]);
    if (quad == 0) { bq[0] = c2[0]; bq[1] = c2[1]; }
  }
  const v4h ones = (v4h){(_Float16)1.f, (_Float16)1.f,
                         (_Float16)1.f, (_Float16)1.f};

  v4f o[4];
#pragma unroll
  for (int nt = 0; nt < 4; ++nt) o[nt] = (v4f){0.f, 0.f, 0.f, 0.f};
  v4f lacc = (v4f){0.f, 0.f, 0.f, 0.f};

  const _Float16* Kb   = K + (size_t)(b * LL) * DD + h * 64;     // row stride 1024
  const _Float16* VTb2 = VT2 + (size_t)bh * 131072;              // 32 tiles x 4096
  const unsigned* csk = csh2 + csb;
  const float* amb = aml2 + b * LL;

  const int srow = tid >> 3;                // 0..31 K staging row
  const int kch  = (tid & 7) ^ (srow & 7);  // swizzled source 16B chunk (K only)
  const size_t kgb = (size_t)srow * 1024 + kch * 8;

  // prologue: K0 -> Kt[0], V0 -> Vt[0], K1 -> Kt[1] (depth-2)
  {
    GLD(Kb + kgb,             &Kt[0][tid * 8]);
    GLD(Kb + kgb + 32 * 1024, &Kt[0][2048 + tid * 8]);
    GLD(VTb2 + tid * 8,           &Vt[0][tid * 8]);
    GLD(VTb2 + 2048 + tid * 8,    &Vt[0][2048 + tid * 8]);
    GLD(Kb + kgb + 64 * 1024, &Kt[1][tid * 8]);
    GLD(Kb + kgb + 96 * 1024, &Kt[1][2048 + tid * 8]);
  }
  unsigned cs_cur[4], cs_nxt[4];
  v4f am_cur[4], am_nxt[4];
#pragma unroll
  for (int c = 0; c < 4; ++c) {
    cs_cur[c] = csk[c * 16 + ql];
    am_cur[c] = *(const v4f*)&amb[c * 16 + quad * 4];
  }
  __builtin_amdgcn_sched_barrier(0);
  asm volatile("s_waitcnt vmcnt(2)" ::: "memory");  // K0,V0 done; K1 in flight
  __builtin_amdgcn_sched_barrier(0);
  __builtin_amdgcn_s_barrier();
  __builtin_amdgcn_sched_barrier(0);

  int kc = 0;                               // Kt buffer for tile t
  for (int t = 0; t < 32; ++t) {
    const int k0 = t * 64;
    const int vb = t & 1;
    if (t < 31) {
      const int k1 = k0 + 64;
#pragma unroll
      for (int c = 0; c < 4; ++c) {
        cs_nxt[c] = csk[k1 + c * 16 + ql];
        am_nxt[c] = *(const v4f*)&amb[k1 + c * 16 + quad * 4];
      }
      const _Float16* vsrc = VTb2 + (size_t)(t + 1) * 4096;
      GLD(vsrc + tid * 8,        &Vt[vb ^ 1][tid * 8]);
      GLD(vsrc + 2048 + tid * 8, &Vt[vb ^ 1][2048 + tid * 8]);
      if (t < 30) {
        const int kn = (kc == 0) ? 2 : kc - 1;      // (kc+2)%3
        const size_t kg = kgb + (size_t)(k0 + 128) * 1024;
        GLD(Kb + kg,             &Kt[kn][tid * 8]);
        GLD(Kb + kg + 32 * 1024, &Kt[kn][2048 + tid * 8]);
      }
    }
    const _Float16* KtB = Kt[kc];
    const _Float16* VtB = Vt[vb];

    // --- S^T (log2 domain) + mask-dot MFMA ---
    v4f st[4], dd[4];
#pragma unroll
    for (int c = 0; c < 4; ++c) {
      const int row = c * 16 + ql;
      const int sw = row & 7;
      v8h a0 = *(const v8h*)&KtB[row * 64 + ((quad ^ sw) << 3)];
      v8h a1 = *(const v8h*)&KtB[row * 64 + (((quad + 4) ^ sw) << 3)];
      v4f z = (v4f){0.f, 0.f, 0.f, 0.f};
      z = __builtin_amdgcn_mfma_f32_16x16x32_f16(a0, qf[0], z, 0, 0, 0);
      z = __builtin_amdgcn_mfma_f32_16x16x32_f16(a1, qf[1], z, 0, 0, 0);
      st[c] = z;
      const v2h c2 = __builtin_bit_cast(v2h, cs_cur[c]);
      v4h a = (v4h){0, 0, 0, 0};
      if (quad == 0) { a[0] = c2[0]; a[1] = c2[1]; }
      dd[c] = __builtin_amdgcn_mfma_f32_16x16x16f16(
          a, bq, (v4f){0.f, 0.f, 0.f, 0.f}, 0, 0, 0);
    }

    // --- mask + P = exp2(score) (no max subtraction; scores bounded) ---
    v4h pf[4];
    const bool hasdiag = ((unsigned)(q0w - k0)) < 64u;  // wave-uniform
    if (hasdiag) {
#pragma unroll
      for (int c = 0; c < 4; ++c) {
        float p[4];
#pragma unroll
        for (int r = 0; r < 4; ++r) {
          const bool msk = (dd[c][r] < -0.7f) &&
                           ((k0 + c * 16 + quad * 4 + r) != qglob);
          p[r] = __builtin_amdgcn_exp2f((msk ? NEGB : st[c][r]) + am_cur[c][r]);
        }
        const unsigned u01 = __builtin_bit_cast(
            unsigned, __builtin_amdgcn_cvt_pkrtz(p[0], p[1]));
        const unsigned u23 = __builtin_bit_cast(
            unsigned, __builtin_amdgcn_cvt_pkrtz(p[2], p[3]));
        pf[c] = __builtin_bit_cast(v4h, make_uint2(u01, u23));
      }
    } else {
#pragma unroll
      for (int c = 0; c < 4; ++c) {
        float p[4];
#pragma unroll
        for (int r = 0; r < 4; ++r) {
          p[r] = __builtin_amdgcn_exp2f(
              ((dd[c][r] < -0.7f) ? NEGB : st[c][r]) + am_cur[c][r]);
        }
        const unsigned u01 = __builtin_bit_cast(
            unsigned, __builtin_amdgcn_cvt_pkrtz(p[0], p[1]));
        const unsigned u23 = __builtin_bit_cast(
            unsigned, __builtin_amdgcn_cvt_pkrtz(p[2], p[3]));
        pf[c] = __builtin_bit_cast(v4h, make_uint2(u01, u23));
      }
    }

    // --- PV + row-sum (both on the MFMA pipe) ---
#pragma unroll
    for (int c = 0; c < 4; ++c) {
      lacc = __builtin_amdgcn_mfma_f32_16x16x16f16(pf[c], ones, lacc, 0, 0, 0);
#pragma unroll
      for (int nt = 0; nt < 4; ++nt) {
        const v4h vv = *(const v4h*)&VtB[((c * 4 + quad) * 64 +
                                          nt * 16 + ql) * 4];
        o[nt] = __builtin_amdgcn_mfma_f32_16x16x16f16(pf[c], vv, o[nt], 0, 0, 0);
      }
    }

    if (t < 31) {
#pragma unroll
      for (int c = 0; c < 4; ++c) {       // consumes cs/am prefetch loads
        cs_cur[c] = cs_nxt[c];
        am_cur[c] = am_nxt[c];
      }
      __builtin_amdgcn_sched_barrier(0);
      if (t < 30) asm volatile("s_waitcnt vmcnt(2)" ::: "memory"); // K[t+2] stays in flight
      else        asm volatile("s_waitcnt vmcnt(0)" ::: "memory"); // last: drain V[31]
      __builtin_amdgcn_sched_barrier(0);
      __builtin_amdgcn_s_barrier();
      __builtin_amdgcn_sched_barrier(0);
    }
    kc = (kc == 2) ? 0 : kc + 1;
  }

  // epilogue: lacc is already in O's row layout (query = quad*4+r)
#pragma unroll
  for (int r = 0; r < 4; ++r) {
    const int q = q0w + quad * 4 + r;
    const float lr = lacc[r];
    const size_t ob = (size_t)(b * LL + q) * DD + h * 64 + ql;
    if (lr <= 0.f) {  // all-masked fallback (never taken with am=0)
      const _Float16* vsrc = VTb2 + (q >> 6) * 4096 +
                             ((q >> 2) & 15) * 256 + (q & 3);
#pragma unroll
      for (int nt = 0; nt < 4; ++nt)
        ctx[ob + nt * 16] = vsrc[(nt * 16 + ql) * 4];
    } else {
      const float inv = 1.f / lr;
      ctx[ob + 0]  = (_Float16)(o[0][r] * inv);
      ctx[ob + 16] = (_Float16)(o[1][r] * inv);
      ctx[ob + 32] = (_Float16)(o[2][r] * inv);
      ctx[ob + 48] = (_Float16)(o[3][r] * inv);
    }
  }
}

// ---------------------------------------------------------------------------
// LayerNorm over D=1024
// ---------------------------------------------------------------------------
__global__ __launch_bounds__(256) void layernorm(
    const float* __restrict__ x, const float* __restrict__ g,
    const float* __restrict__ bta, float* __restrict__ out)
{
  __shared__ float red[8];
  const int row = blockIdx.x;
  const int tid = threadIdx.x;
  const float* xr = x + (size_t)row * DD;
  float lsum = 0.f, lsq = 0.f;
  float v[4];
#pragma unroll
  for (int i = 0; i < 4; ++i) {
    v[i] = xr[tid + i * 256];
    lsum += v[i];
    lsq += v[i] * v[i];
  }
#pragma unroll
  for (int off = 32; off > 0; off >>= 1) {
    lsum += __shfl_down(lsum, off, 64);
    lsq  += __shfl_down(lsq,  off, 64);
  }
  const int wid = tid >> 6;
  if ((tid & 63) == 0) { red[wid] = lsum; red[wid + 4] = lsq; }
  __syncthreads();
  const float tsum = red[0] + red[1] + red[2] + red[3];
  const float tsq  = red[4] + red[5] + red[6] + red[7];
  const float mean = tsum * (1.f / DD);
  const float var  = tsq * (1.f / DD) - mean * mean;
  const float inv  = rsqrtf(var + 1e-12f);
#pragma unroll
  for (int i = 0; i < 4; ++i) {
    const int c = tid + i * 256;
    out[(size_t)row * DD + c] = (v[i] - mean) * inv * g[c] + bta[c];
  }
}

// ---------------------------------------------------------------------------
extern "C" void kernel_launch(void* const* d_in, const int* in_sizes, int n_in,
                              void* d_out, int out_size, void* d_ws, size_t ws_size,
                              hipStream_t stream)
{
  const float* hs  = (const float*)d_in[0];
  const float* amk = (const float*)d_in[1];
  const float* phi = (const float*)d_in[2];
  const float* Wq  = (const float*)d_in[3];
  const float* bq  = (const float*)d_in[4];
  const float* Wk  = (const float*)d_in[5];
  const float* bk  = (const float*)d_in[6];
  const float* Wv  = (const float*)d_in[7];
  const float* bv  = (const float*)d_in[8];
  const float* Wo  = (const float*)d_in[9];
  const float* bo  = (const float*)d_in[10];
  const float* lng = (const float*)d_in[11];
  const float* lnb = (const float*)d_in[12];
  float* out = (float*)d_out;

  const size_t SZ = (size_t)BB * LL * DD;   // 4 M elements
  _Float16* hsh   = (_Float16*)d_ws;
  _Float16* qh    = hsh + SZ;
  _Float16* kh    = qh + SZ;
  _Float16* vt2   = kh + SZ;                // 4 M (V pre-tiled VT2)
  _Float16* ctxh  = vt2 + SZ;
  _Float16* wqkvh = ctxh + SZ;              // 3 M
  _Float16* woh   = wqkvh + 3 * (size_t)DD * DD;  // 1 M
  float* xb    = (float*)(woh + (size_t)DD * DD);
  unsigned* csh2 = (unsigned*)(xb + SZ);    // B*H*L packed {cos,sin} f16
  float* aml2 = (float*)(csh2 + (size_t)BB * HH * LL);  // B*L am*log2e

  cvt_all<<<8192, 256, 0, stream>>>(hs, Wq, Wk, Wv, Wo, hsh, wqkvh, woh);
  csgen<<<256, 256, 0, stream>>>(phi, amk, csh2, aml2);
  gemm_qkv<<<dim3(24, 32), 256, 0, stream>>>(hsh, wqkvh, bq, bk, bv, csh2,
                                             qh, kh, vt2);
  attn_db<<<1024, 256, 0, stream>>>(qh, kh, vt2, csh2, aml2, ctxh);
  gemm_o<<<dim3(16, 32), 256, 0, stream>>>(ctxh, woh, bo, hs, xb);
  layernorm<<<BB * LL, 256, 0, stream>>>(xb, lng, lnb, out);
}

// Round 2
// 240.252 us; speedup vs baseline: 1.0360x; 1.0103x over previous
//
#include <hip/hip_runtime.h>
#include <cmath>

#define BB 2
#define LL 2048
#define DD 1024
#define HH 16
#define HDD 64

typedef _Float16 v8h __attribute__((ext_vector_type(8)));
typedef _Float16 v4h __attribute__((ext_vector_type(4)));
typedef _Float16 v2h __attribute__((ext_vector_type(2)));
typedef float v4f __attribute__((ext_vector_type(4)));

#define LOG2E 1.44269504089f
#define NEGB  (-1.442695e9f)      /* -1e9 * log2e */

// async global->LDS, 16B per lane.
#define GLD(gp, lp)                                                        \
  __builtin_amdgcn_global_load_lds(                                        \
      (const __attribute__((address_space(1))) void*)(gp),                 \
      (__attribute__((address_space(3))) void*)(lp), 16, 0, 0)

// ---------------------------------------------------------------------------
// fp32 -> f16 conversion: hs + Wq/Wk/Wv (into wqkvh) + Wo.
// ---------------------------------------------------------------------------
__global__ __launch_bounds__(256) void cvt_all(
    const float* __restrict__ hs, const float* __restrict__ wq,
    const float* __restrict__ wk, const float* __restrict__ wv,
    const float* __restrict__ wo, _Float16* __restrict__ hsh,
    _Float16* __restrict__ wqkvh, _Float16* __restrict__ woh)
{
  const int i = blockIdx.x * 256 + threadIdx.x;
  const float* s;
  _Float16* d;
  if (i < 1048576)      { s = hs + (size_t)i * 4;            d = hsh + (size_t)i * 4; }
  else if (i < 1310720) { int j = i - 1048576; s = wq + (size_t)j * 4; d = wqkvh + (size_t)j * 4; }
  else if (i < 1572864) { int j = i - 1310720; s = wk + (size_t)j * 4; d = wqkvh + 1048576 + (size_t)j * 4; }
  else if (i < 1835008) { int j = i - 1572864; s = wv + (size_t)j * 4; d = wqkvh + 2097152 + (size_t)j * 4; }
  else                  { int j = i - 1835008; s = wo + (size_t)j * 4; d = woh + (size_t)j * 4; }
  float4 v = *(const float4*)s;
  v4h o;
  o[0] = (_Float16)v.x; o[1] = (_Float16)v.y;
  o[2] = (_Float16)v.z; o[3] = (_Float16)v.w;
  *(v4h*)d = o;
}

// ---------------------------------------------------------------------------
// cos/sin table from phi: csh2[(b*16+h)*2048 + l] = packed f16 {cos, sin}.
// Also writes aml2[b*2048+l] = am * log2e (attn copies it to LDS per block).
// ---------------------------------------------------------------------------
__global__ __launch_bounds__(256) void csgen(
    const float* __restrict__ phi, const float* __restrict__ amk,
    unsigned* __restrict__ csh2, float* __restrict__ aml2)
{
  const int o = blockIdx.x * 256 + threadIdx.x;  // 65536 = B*H*L
  if (o < BB * LL) aml2[o] = amk[o] * LOG2E;
  const int l = o & 2047;
  const int h = (o >> 11) & 15;
  const int b = o >> 15;
  const float ph = phi[(b * 2048 + l) * 16 + h];
  v2h cs;
  cs[0] = (_Float16)cosf(ph);
  cs[1] = (_Float16)sinf(ph);
  csh2[o] = __builtin_bit_cast(unsigned, cs);
}

// ---------------------------------------------------------------------------
// m97-style MFMA GEMM core: 128x128 tile, BK=32, 256 thr.
// ---------------------------------------------------------------------------
__device__ __forceinline__ void gemm_loop(
    const _Float16* __restrict__ A, const _Float16* __restrict__ W, const int K,
    const int m0, const int n0, const int tid, const int wave, const int lane,
    _Float16* As, _Float16* Bs, v4f acc[4][4])
{
  const int quad = lane >> 4;
  const int ql = lane & 15;
  const int wm = (wave >> 1) * 64;
  const int wn = (wave & 1) * 64;
  const int srow = tid >> 2;
  const int skof = (tid & 3) * 8;
  const _Float16* Ap = A + (size_t)(m0 + srow) * K + skof;
  const _Float16* Wp = W + (size_t)(n0 + srow) * K + skof;
  const size_t rstep = (size_t)64 * K;
  for (int k0 = 0; k0 < K; k0 += 32) {
    __syncthreads();
    GLD(Ap + k0,         As + tid * 8);
    GLD(Ap + rstep + k0, As + 2048 + tid * 8);
    GLD(Wp + k0,         Bs + tid * 8);
    GLD(Wp + rstep + k0, Bs + 2048 + tid * 8);
    __syncthreads();
    v8h af[4], bf[4];
#pragma unroll
    for (int mt = 0; mt < 4; ++mt)
      af[mt] = *(const v8h*)&As[(wm + mt * 16 + ql) * 32 + quad * 8];
#pragma unroll
    for (int nt = 0; nt < 4; ++nt)
      bf[nt] = *(const v8h*)&Bs[(wn + nt * 16 + ql) * 32 + quad * 8];
#pragma unroll
    for (int mt = 0; mt < 4; ++mt)
#pragma unroll
      for (int nt = 0; nt < 4; ++nt)
        acc[mt][nt] = __builtin_amdgcn_mfma_f32_16x16x32_f16(
            af[mt], bf[nt], acc[mt][nt], 0, 0, 0);
  }
}

// ---------------------------------------------------------------------------
// Fused QKV GEMM. Epilogue:
//   q-band: +bias, rotary (fp32), scale by (1/8)*log2e, single f16 rounding
//   k-band: +bias, rotary (fp32), f16
//   v-band: +bias, written directly in VT2 layout (8B unit [j=key>>2][d])
// ---------------------------------------------------------------------------
__global__ __launch_bounds__(256) void gemm_qkv(
    const _Float16* __restrict__ A, const _Float16* __restrict__ W,
    const float* __restrict__ bqp, const float* __restrict__ bkp,
    const float* __restrict__ bvp, const unsigned* __restrict__ csh2,
    _Float16* __restrict__ qh, _Float16* __restrict__ kh,
    _Float16* __restrict__ vt2)
{
  __shared__ _Float16 As[128 * 32];
  __shared__ _Float16 Bs[128 * 32];
  const int tid = threadIdx.x, lane = tid & 63, wave = tid >> 6;
  const int quad = lane >> 4, ql = lane & 15;
  const int m0 = blockIdx.y * 128, n0 = blockIdx.x * 128;
  v4f acc[4][4];
#pragma unroll
  for (int mt = 0; mt < 4; ++mt)
#pragma unroll
    for (int nt = 0; nt < 4; ++nt) acc[mt][nt] = (v4f){0.f, 0.f, 0.f, 0.f};
  gemm_loop(A, W, DD, m0, n0, tid, wave, lane, As, Bs, acc);

  const int buf = n0 >> 10;                       // 0=q 1=k 2=v
  const int col0 = (n0 & 1023) + (wave & 1) * 64; // 64-col band == one head
  const int hh = col0 >> 6;
  const int mr0 = m0 + (wave >> 1) * 64;

  if (buf == 2) {
    float bb4[4];
#pragma unroll
    for (int nt = 0; nt < 4; ++nt) bb4[nt] = bvp[col0 + nt * 16 + ql];
#pragma unroll
    for (int mt = 0; mt < 4; ++mt) {
      const int row = mr0 + mt * 16 + quad * 4;   // keys row..row+3
      const int b_ = row >> 11;
      const int l = row & 2047;
      _Float16* dst = vt2 + ((size_t)(b_ * 16 + hh) * 32 + (l >> 6)) * 4096 +
                      ((l >> 2) & 15) * 256;
#pragma unroll
      for (int nt = 0; nt < 4; ++nt) {
        const int d = nt * 16 + ql;
        v4h o4;
#pragma unroll
        for (int r = 0; r < 4; ++r) o4[r] = (_Float16)(acc[mt][nt][r] + bb4[nt]);
        *(v4h*)&dst[d * 4] = o4;
      }
    }
  } else {
    const float scl = (buf == 0) ? 0.125f * LOG2E : 1.0f;
    _Float16* outp = (buf == 0) ? qh : kh;
    const float* bias = (buf == 0) ? bqp : bkp;
    float bb4[4];
#pragma unroll
    for (int nt = 0; nt < 4; ++nt) bb4[nt] = bias[col0 + nt * 16 + ql];
#pragma unroll
    for (int mt = 0; mt < 4; ++mt)
#pragma unroll
      for (int r = 0; r < 4; ++r) {
        const int row = mr0 + mt * 16 + quad * 4 + r;
        const int b_ = row >> 11;
        const int l = row & 2047;
        const v2h c2 = __builtin_bit_cast(
            v2h, csh2[(b_ * 16 + hh) * 2048 + l]);
        const float c = (float)c2[0], s = (float)c2[1];
        _Float16* orow = outp + (size_t)row * DD + col0 + ql;
#pragma unroll
        for (int pp = 0; pp < 2; ++pp) {
          const float a0 = acc[mt][pp][r] + bb4[pp];
          const float a1 = acc[mt][pp + 2][r] + bb4[pp + 2];
          orow[pp * 16]        = (_Float16)((a0 * c - a1 * s) * scl);
          orow[(pp + 2) * 16]  = (_Float16)((a1 * c + a0 * s) * scl);
        }
      }
  }
}

// ---------------------------------------------------------------------------
// O-proj GEMM, 128(M)x64(N) tiles: grid 16x32 = 512 blocks (2/CU).
// ---------------------------------------------------------------------------
__global__ __launch_bounds__(256) void gemm_o(
    const _Float16* __restrict__ A, const _Float16* __restrict__ W,
    const float* __restrict__ bo, const float* __restrict__ res,
    float* __restrict__ out)
{
  __shared__ _Float16 As[128 * 32];
  __shared__ _Float16 Bs[64 * 32];
  const int tid = threadIdx.x, lane = tid & 63, wave = tid >> 6;
  const int quad = lane >> 4, ql = lane & 15;
  const int m0 = blockIdx.y * 128, n0 = blockIdx.x * 64;
  v4f acc[4][2];
#pragma unroll
  for (int mt = 0; mt < 4; ++mt)
#pragma unroll
    for (int nt = 0; nt < 2; ++nt) acc[mt][nt] = (v4f){0.f, 0.f, 0.f, 0.f};
  const int wm = (wave >> 1) * 64;
  const int wn = (wave & 1) * 32;
  const int srow = tid >> 2;
  const int skof = (tid & 3) * 8;
  const _Float16* Ap = A + (size_t)(m0 + srow) * DD + skof;
  const _Float16* Wp = W + (size_t)(n0 + srow) * DD + skof;
  const size_t rstep = (size_t)64 * DD;
  for (int k0 = 0; k0 < DD; k0 += 32) {
    __syncthreads();
    GLD(Ap + k0,         As + tid * 8);
    GLD(Ap + rstep + k0, As + 2048 + tid * 8);
    GLD(Wp + k0,         Bs + tid * 8);
    __syncthreads();
    v8h af[4], bf[2];
#pragma unroll
    for (int mt = 0; mt < 4; ++mt)
      af[mt] = *(const v8h*)&As[(wm + mt * 16 + ql) * 32 + quad * 8];
#pragma unroll
    for (int nt = 0; nt < 2; ++nt)
      bf[nt] = *(const v8h*)&Bs[(wn + nt * 16 + ql) * 32 + quad * 8];
#pragma unroll
    for (int mt = 0; mt < 4; ++mt)
#pragma unroll
      for (int nt = 0; nt < 2; ++nt)
        acc[mt][nt] = __builtin_amdgcn_mfma_f32_16x16x32_f16(
            af[mt], bf[nt], acc[mt][nt], 0, 0, 0);
  }
#pragma unroll
  for (int nt = 0; nt < 2; ++nt) {
    const int col = n0 + wn + nt * 16 + ql;
    const float bb = bo[col];
#pragma unroll
    for (int mt = 0; mt < 4; ++mt)
#pragma unroll
      for (int r = 0; r < 4; ++r) {
        const int row = m0 + wm + mt * 16 + quad * 4 + r;
        const size_t ix = (size_t)row * DD + col;
        out[ix] = acc[mt][nt][r] + bb + res[ix];
      }
  }
}

// ---------------------------------------------------------------------------
// Double-buffered LDS flash attention, no online-max (scores bounded).
// Round-0 __syncthreads structure (measured-best: VALU+MFMA ~98% combined),
// with the VALU-cut epilogue:
//   * am*log2e folded into the QK MFMA C-init (C/D rows = keys, so the
//     per-key am broadcast lands exactly; the 16 per-element adds vanish).
//   * diagonal exception deleted: mask dot on the diagonal is c^2+s^2 of
//     IDENTICAL f16 table entries = 1 +- 2e-3, can never cross -0.7.
//   * exp2 path is cmp + cndmask + exp2 only.
// Row-sum via MFMA with ones B-fragment (lands in C-layout rows); final
// O/lrow. All-masked fallback <=> lrow == 0.
// ---------------------------------------------------------------------------
__global__ __launch_bounds__(256) void attn_db(
    const _Float16* __restrict__ Q, const _Float16* __restrict__ K,
    const _Float16* __restrict__ VT2, const unsigned* __restrict__ csh2,
    const float* __restrict__ aml2, _Float16* __restrict__ ctx)
{
  __shared__ _Float16 Kt[2][4096];   // [buf] 64 rows x 64 dims (16B-swizzled)
  __shared__ _Float16 Vt[2][4096];   // [buf] VT2 tile image (8B units j-major)
  __shared__ float amL[LL];          // am * log2e, whole row: 8 KB

  const int tid  = threadIdx.x;
  const int lane = tid & 63;
  const int wave = tid >> 6;
  const int quad = lane >> 4;
  const int ql   = lane & 15;
  const int bid  = blockIdx.x;       // 1024 = 32 qt * 32 bh
  const int bh = bid & 31;           // XCD swizzle: same (b,h) -> same XCD
  const int qt = bid >> 5;
  const int h  = bh & 15;
  const int b  = bh >> 4;
  const int q0w = qt * 64 + wave * 16;
  const int qglob = q0w + ql;
  const int csb = bh * LL;

  {
    const float* amb = aml2 + b * LL;
    for (int i = tid; i < LL; i += 256) amL[i] = amb[i];
  }

  // Q B-fragment (bias+rotary+log2e/8 pre-folded at GEMM epilogue)
  v8h qf[2];
  {
    const _Float16* qp = Q + ((size_t)(b * LL + qglob)) * DD + h * 64 + quad * 8;
    qf[0] = *(const v8h*)qp;
    qf[1] = *(const v8h*)(qp + 32);
  }
  // {cos_q, sin_q} B-fragment for the mask MFMA
  v4h bq = (v4h){0, 0, 0, 0};
  {
    const v2h c2 = __builtin_bit_cast(v2h, csh2[csb + qglob]);
    if (quad == 0) { bq[0] = c2[0]; bq[1] = c2[1]; }
  }
  const v4h ones = (v4h){(_Float16)1.f, (_Float16)1.f,
                         (_Float16)1.f, (_Float16)1.f};

  v4f o[4];
#pragma unroll
  for (int nt = 0; nt < 4; ++nt) o[nt] = (v4f){0.f, 0.f, 0.f, 0.f};
  v4f lacc = (v4f){0.f, 0.f, 0.f, 0.f};

  const _Float16* Kb   = K + (size_t)(b * LL) * DD + h * 64;     // row stride 1024
  const _Float16* VTb2 = VT2 + (size_t)bh * 131072;              // 32 tiles x 4096
  const unsigned* csk = csh2 + csb;

  const int srow = tid >> 3;                // 0..31 K staging row
  const int kch  = (tid & 7) ^ (srow & 7);  // swizzled source 16B chunk (K only)

  // prologue: tile 0 -> buf 0; csk for tile 0 -> registers
  {
    const size_t kg = (size_t)srow * 1024 + kch * 8;
    GLD(Kb + kg,             &Kt[0][tid * 8]);
    GLD(Kb + kg + 32 * 1024, &Kt[0][2048 + tid * 8]);
    GLD(VTb2 + tid * 8,          &Vt[0][tid * 8]);
    GLD(VTb2 + 2048 + tid * 8,   &Vt[0][2048 + tid * 8]);
  }
  unsigned cs_cur[4], cs_nxt[4];
#pragma unroll
  for (int c = 0; c < 4; ++c) cs_cur[c] = csk[c * 16 + ql];
  __syncthreads();

  for (int t = 0; t < 32; ++t) {
    const int k0 = t * 64;
    const int buf = t & 1;
    if (t < 31) {
      const int k1 = k0 + 64;
      const size_t kg = (size_t)(k1 + srow) * 1024 + kch * 8;
      GLD(Kb + kg,             &Kt[buf ^ 1][tid * 8]);
      GLD(Kb + kg + 32 * 1024, &Kt[buf ^ 1][2048 + tid * 8]);
      const _Float16* vsrc = VTb2 + (size_t)(t + 1) * 4096;
      GLD(vsrc + tid * 8,        &Vt[buf ^ 1][tid * 8]);
      GLD(vsrc + 2048 + tid * 8, &Vt[buf ^ 1][2048 + tid * 8]);
#pragma unroll
      for (int c = 0; c < 4; ++c) cs_nxt[c] = csk[k1 + c * 16 + ql];
    }
    const _Float16* KtB = Kt[buf];
    const _Float16* VtB = Vt[buf];

    // --- S^T (log2 domain, am pre-added via C-init) + mask-dot MFMA ---
    v4f st[4], dd[4];
#pragma unroll
    for (int c = 0; c < 4; ++c) {
      const int row = c * 16 + ql;
      const int sw = row & 7;
      v8h a0 = *(const v8h*)&KtB[row * 64 + ((quad ^ sw) << 3)];
      v8h a1 = *(const v8h*)&KtB[row * 64 + (((quad + 4) ^ sw) << 3)];
      v4f z = *(const v4f*)&amL[k0 + c * 16 + quad * 4];  // C-init = am*log2e
      z = __builtin_amdgcn_mfma_f32_16x16x32_f16(a0, qf[0], z, 0, 0, 0);
      z = __builtin_amdgcn_mfma_f32_16x16x32_f16(a1, qf[1], z, 0, 0, 0);
      st[c] = z;
      const v2h c2 = __builtin_bit_cast(v2h, cs_cur[c]);
      v4h a = (v4h){0, 0, 0, 0};
      if (quad == 0) { a[0] = c2[0]; a[1] = c2[1]; }
      dd[c] = __builtin_amdgcn_mfma_f32_16x16x16f16(
          a, bq, (v4f){0.f, 0.f, 0.f, 0.f}, 0, 0, 0);
    }

    // --- mask + P = exp2(score): cmp + cndmask + exp2 only ---
    v4h pf[4];
#pragma unroll
    for (int c = 0; c < 4; ++c) {
      float p[4];
#pragma unroll
      for (int r = 0; r < 4; ++r)
        p[r] = __builtin_amdgcn_exp2f((dd[c][r] < -0.7f) ? NEGB : st[c][r]);
      const unsigned u01 = __builtin_bit_cast(
          unsigned, __builtin_amdgcn_cvt_pkrtz(p[0], p[1]));
      const unsigned u23 = __builtin_bit_cast(
          unsigned, __builtin_amdgcn_cvt_pkrtz(p[2], p[3]));
      pf[c] = __builtin_bit_cast(v4h, make_uint2(u01, u23));
    }

    // --- PV + row-sum (both on the MFMA pipe) ---
#pragma unroll
    for (int c = 0; c < 4; ++c) {
      lacc = __builtin_amdgcn_mfma_f32_16x16x16f16(pf[c], ones, lacc, 0, 0, 0);
#pragma unroll
      for (int nt = 0; nt < 4; ++nt) {
        const v4h vv = *(const v4h*)&VtB[((c * 4 + quad) * 64 +
                                          nt * 16 + ql) * 4];
        o[nt] = __builtin_amdgcn_mfma_f32_16x16x16f16(pf[c], vv, o[nt], 0, 0, 0);
      }
    }
#pragma unroll
    for (int c = 0; c < 4; ++c) cs_cur[c] = cs_nxt[c];
    __syncthreads();
  }

  // epilogue: lacc is already in O's row layout (query = quad*4+r)
#pragma unroll
  for (int r = 0; r < 4; ++r) {
    const int q = q0w + quad * 4 + r;
    const float lr = lacc[r];
    const size_t ob = (size_t)(b * LL + q) * DD + h * 64 + ql;
    if (lr <= 0.f) {  // all-masked fallback (never taken with am=0)
      const _Float16* vsrc = VTb2 + (q >> 6) * 4096 +
                             ((q >> 2) & 15) * 256 + (q & 3);
#pragma unroll
      for (int nt = 0; nt < 4; ++nt)
        ctx[ob + nt * 16] = vsrc[(nt * 16 + ql) * 4];
    } else {
      const float inv = 1.f / lr;
      ctx[ob + 0]  = (_Float16)(o[0][r] * inv);
      ctx[ob + 16] = (_Float16)(o[1][r] * inv);
      ctx[ob + 32] = (_Float16)(o[2][r] * inv);
      ctx[ob + 48] = (_Float16)(o[3][r] * inv);
    }
  }
}

// ---------------------------------------------------------------------------
// LayerNorm over D=1024
// ---------------------------------------------------------------------------
__global__ __launch_bounds__(256) void layernorm(
    const float* __restrict__ x, const float* __restrict__ g,
    const float* __restrict__ bta, float* __restrict__ out)
{
  __shared__ float red[8];
  const int row = blockIdx.x;
  const int tid = threadIdx.x;
  const float* xr = x + (size_t)row * DD;
  float lsum = 0.f, lsq = 0.f;
  float v[4];
#pragma unroll
  for (int i = 0; i < 4; ++i) {
    v[i] = xr[tid + i * 256];
    lsum += v[i];
    lsq += v[i] * v[i];
  }
#pragma unroll
  for (int off = 32; off > 0; off >>= 1) {
    lsum += __shfl_down(lsum, off, 64);
    lsq  += __shfl_down(lsq,  off, 64);
  }
  const int wid = tid >> 6;
  if ((tid & 63) == 0) { red[wid] = lsum; red[wid + 4] = lsq; }
  __syncthreads();
  const float tsum = red[0] + red[1] + red[2] + red[3];
  const float tsq  = red[4] + red[5] + red[6] + red[7];
  const float mean = tsum * (1.f / DD);
  const float var  = tsq * (1.f / DD) - mean * mean;
  const float inv  = rsqrtf(var + 1e-12f);
#pragma unroll
  for (int i = 0; i < 4; ++i) {
    const int c = tid + i * 256;
    out[(size_t)row * DD + c] = (v[i] - mean) * inv * g[c] + bta[c];
  }
}

// ---------------------------------------------------------------------------
extern "C" void kernel_launch(void* const* d_in, const int* in_sizes, int n_in,
                              void* d_out, int out_size, void* d_ws, size_t ws_size,
                              hipStream_t stream)
{
  const float* hs  = (const float*)d_in[0];
  const float* amk = (const float*)d_in[1];
  const float* phi = (const float*)d_in[2];
  const float* Wq  = (const float*)d_in[3];
  const float* bq  = (const float*)d_in[4];
  const float* Wk  = (const float*)d_in[5];
  const float* bk  = (const float*)d_in[6];
  const float* Wv  = (const float*)d_in[7];
  const float* bv  = (const float*)d_in[8];
  const float* Wo  = (const float*)d_in[9];
  const float* bo  = (const float*)d_in[10];
  const float* lng = (const float*)d_in[11];
  const float* lnb = (const float*)d_in[12];
  float* out = (float*)d_out;

  const size_t SZ = (size_t)BB * LL * DD;   // 4 M elements
  _Float16* hsh   = (_Float16*)d_ws;
  _Float16* qh    = hsh + SZ;
  _Float16* kh    = qh + SZ;
  _Float16* vt2   = kh + SZ;                // 4 M (V pre-tiled VT2)
  _Float16* ctxh  = vt2 + SZ;
  _Float16* wqkvh = ctxh + SZ;              // 3 M
  _Float16* woh   = wqkvh + 3 * (size_t)DD * DD;  // 1 M
  float* xb    = (float*)(woh + (size_t)DD * DD);
  unsigned* csh2 = (unsigned*)(xb + SZ);    // B*H*L packed {cos,sin} f16
  float* aml2 = (float*)(csh2 + (size_t)BB * HH * LL);  // B*L am*log2e

  cvt_all<<<8192, 256, 0, stream>>>(hs, Wq, Wk, Wv, Wo, hsh, wqkvh, woh);
  csgen<<<256, 256, 0, stream>>>(phi, amk, csh2, aml2);
  gemm_qkv<<<dim3(24, 32), 256, 0, stream>>>(hsh, wqkvh, bq, bk, bv, csh2,
                                             qh, kh, vt2);
  attn_db<<<1024, 256, 0, stream>>>(qh, kh, vt2, csh2, aml2, ctxh);
  gemm_o<<<dim3(16, 32), 256, 0, stream>>>(ctxh, woh, bo, hs, xb);
  layernorm<<<BB * LL, 256, 0, stream>>>(xb, lng, lnb, out);
}

// Round 3
// 232.775 us; speedup vs baseline: 1.0692x; 1.0321x over previous
//
#include <hip/hip_runtime.h>
#include <cmath>

#define BB 2
#define LL 2048
#define DD 1024
#define HH 16
#define HDD 64

typedef _Float16 v8h __attribute__((ext_vector_type(8)));
typedef _Float16 v4h __attribute__((ext_vector_type(4)));
typedef _Float16 v2h __attribute__((ext_vector_type(2)));
typedef float v4f __attribute__((ext_vector_type(4)));

#define LOG2E 1.44269504089f
#define NEGB  (-1.442695e9f)      /* -1e9 * log2e */

// async global->LDS, 16B per lane.
#define GLD(gp, lp)                                                        \
  __builtin_amdgcn_global_load_lds(                                        \
      (const __attribute__((address_space(1))) void*)(gp),                 \
      (__attribute__((address_space(3))) void*)(lp), 16, 0, 0)

// ---------------------------------------------------------------------------
// fp32 -> f16 conversion: hs + Wq/Wk/Wv (into wqkvh) + Wo.
// ---------------------------------------------------------------------------
__global__ __launch_bounds__(256) void cvt_all(
    const float* __restrict__ hs, const float* __restrict__ wq,
    const float* __restrict__ wk, const float* __restrict__ wv,
    const float* __restrict__ wo, _Float16* __restrict__ hsh,
    _Float16* __restrict__ wqkvh, _Float16* __restrict__ woh)
{
  const int i = blockIdx.x * 256 + threadIdx.x;
  const float* s;
  _Float16* d;
  if (i < 1048576)      { s = hs + (size_t)i * 4;            d = hsh + (size_t)i * 4; }
  else if (i < 1310720) { int j = i - 1048576; s = wq + (size_t)j * 4; d = wqkvh + (size_t)j * 4; }
  else if (i < 1572864) { int j = i - 1310720; s = wk + (size_t)j * 4; d = wqkvh + 1048576 + (size_t)j * 4; }
  else if (i < 1835008) { int j = i - 1572864; s = wv + (size_t)j * 4; d = wqkvh + 2097152 + (size_t)j * 4; }
  else                  { int j = i - 1835008; s = wo + (size_t)j * 4; d = woh + (size_t)j * 4; }
  float4 v = *(const float4*)s;
  v4h o;
  o[0] = (_Float16)v.x; o[1] = (_Float16)v.y;
  o[2] = (_Float16)v.z; o[3] = (_Float16)v.w;
  *(v4h*)d = o;
}

// ---------------------------------------------------------------------------
// cos/sin table from phi: csh2[(b*16+h)*2048 + l] = packed f16 {cos, sin}.
// Also writes aml2[b*2048+l] = am * log2e (attn copies it to LDS per block).
// ---------------------------------------------------------------------------
__global__ __launch_bounds__(256) void csgen(
    const float* __restrict__ phi, const float* __restrict__ amk,
    unsigned* __restrict__ csh2, float* __restrict__ aml2)
{
  const int o = blockIdx.x * 256 + threadIdx.x;  // 65536 = B*H*L
  if (o < BB * LL) aml2[o] = amk[o] * LOG2E;
  const int l = o & 2047;
  const int h = (o >> 11) & 15;
  const int b = o >> 15;
  const float ph = phi[(b * 2048 + l) * 16 + h];
  v2h cs;
  cs[0] = (_Float16)cosf(ph);
  cs[1] = (_Float16)sinf(ph);
  csh2[o] = __builtin_bit_cast(unsigned, cs);
}

// ---------------------------------------------------------------------------
// m97-style MFMA GEMM core: 128x128 tile, BK=32, 256 thr.
// ---------------------------------------------------------------------------
__device__ __forceinline__ void gemm_loop(
    const _Float16* __restrict__ A, const _Float16* __restrict__ W, const int K,
    const int m0, const int n0, const int tid, const int wave, const int lane,
    _Float16* As, _Float16* Bs, v4f acc[4][4])
{
  const int quad = lane >> 4;
  const int ql = lane & 15;
  const int wm = (wave >> 1) * 64;
  const int wn = (wave & 1) * 64;
  const int srow = tid >> 2;
  const int skof = (tid & 3) * 8;
  const _Float16* Ap = A + (size_t)(m0 + srow) * K + skof;
  const _Float16* Wp = W + (size_t)(n0 + srow) * K + skof;
  const size_t rstep = (size_t)64 * K;
  for (int k0 = 0; k0 < K; k0 += 32) {
    __syncthreads();
    GLD(Ap + k0,         As + tid * 8);
    GLD(Ap + rstep + k0, As + 2048 + tid * 8);
    GLD(Wp + k0,         Bs + tid * 8);
    GLD(Wp + rstep + k0, Bs + 2048 + tid * 8);
    __syncthreads();
    v8h af[4], bf[4];
#pragma unroll
    for (int mt = 0; mt < 4; ++mt)
      af[mt] = *(const v8h*)&As[(wm + mt * 16 + ql) * 32 + quad * 8];
#pragma unroll
    for (int nt = 0; nt < 4; ++nt)
      bf[nt] = *(const v8h*)&Bs[(wn + nt * 16 + ql) * 32 + quad * 8];
#pragma unroll
    for (int mt = 0; mt < 4; ++mt)
#pragma unroll
      for (int nt = 0; nt < 4; ++nt)
        acc[mt][nt] = __builtin_amdgcn_mfma_f32_16x16x32_f16(
            af[mt], bf[nt], acc[mt][nt], 0, 0, 0);
  }
}

// ---------------------------------------------------------------------------
// Fused QKV GEMM. Epilogue:
//   q-band: +bias, rotary (fp32), scale by (1/8)*log2e, single f16 rounding
//   k-band: +bias, rotary (fp32), f16
//   v-band: +bias, written directly in VT2 layout (8B unit [j=key>>2][d])
// ---------------------------------------------------------------------------
__global__ __launch_bounds__(256) void gemm_qkv(
    const _Float16* __restrict__ A, const _Float16* __restrict__ W,
    const float* __restrict__ bqp, const float* __restrict__ bkp,
    const float* __restrict__ bvp, const unsigned* __restrict__ csh2,
    _Float16* __restrict__ qh, _Float16* __restrict__ kh,
    _Float16* __restrict__ vt2)
{
  __shared__ _Float16 As[128 * 32];
  __shared__ _Float16 Bs[128 * 32];
  const int tid = threadIdx.x, lane = tid & 63, wave = tid >> 6;
  const int quad = lane >> 4, ql = lane & 15;
  const int m0 = blockIdx.y * 128, n0 = blockIdx.x * 128;
  v4f acc[4][4];
#pragma unroll
  for (int mt = 0; mt < 4; ++mt)
#pragma unroll
    for (int nt = 0; nt < 4; ++nt) acc[mt][nt] = (v4f){0.f, 0.f, 0.f, 0.f};
  gemm_loop(A, W, DD, m0, n0, tid, wave, lane, As, Bs, acc);

  const int buf = n0 >> 10;                       // 0=q 1=k 2=v
  const int col0 = (n0 & 1023) + (wave & 1) * 64; // 64-col band == one head
  const int hh = col0 >> 6;
  const int mr0 = m0 + (wave >> 1) * 64;

  if (buf == 2) {
    float bb4[4];
#pragma unroll
    for (int nt = 0; nt < 4; ++nt) bb4[nt] = bvp[col0 + nt * 16 + ql];
#pragma unroll
    for (int mt = 0; mt < 4; ++mt) {
      const int row = mr0 + mt * 16 + quad * 4;   // keys row..row+3
      const int b_ = row >> 11;
      const int l = row & 2047;
      _Float16* dst = vt2 + ((size_t)(b_ * 16 + hh) * 32 + (l >> 6)) * 4096 +
                      ((l >> 2) & 15) * 256;
#pragma unroll
      for (int nt = 0; nt < 4; ++nt) {
        const int d = nt * 16 + ql;
        v4h o4;
#pragma unroll
        for (int r = 0; r < 4; ++r) o4[r] = (_Float16)(acc[mt][nt][r] + bb4[nt]);
        *(v4h*)&dst[d * 4] = o4;
      }
    }
  } else {
    const float scl = (buf == 0) ? 0.125f * LOG2E : 1.0f;
    _Float16* outp = (buf == 0) ? qh : kh;
    const float* bias = (buf == 0) ? bqp : bkp;
    float bb4[4];
#pragma unroll
    for (int nt = 0; nt < 4; ++nt) bb4[nt] = bias[col0 + nt * 16 + ql];
#pragma unroll
    for (int mt = 0; mt < 4; ++mt)
#pragma unroll
      for (int r = 0; r < 4; ++r) {
        const int row = mr0 + mt * 16 + quad * 4 + r;
        const int b_ = row >> 11;
        const int l = row & 2047;
        const v2h c2 = __builtin_bit_cast(
            v2h, csh2[(b_ * 16 + hh) * 2048 + l]);
        const float c = (float)c2[0], s = (float)c2[1];
        _Float16* orow = outp + (size_t)row * DD + col0 + ql;
#pragma unroll
        for (int pp = 0; pp < 2; ++pp) {
          const float a0 = acc[mt][pp][r] + bb4[pp];
          const float a1 = acc[mt][pp + 2][r] + bb4[pp + 2];
          orow[pp * 16]        = (_Float16)((a0 * c - a1 * s) * scl);
          orow[(pp + 2) * 16]  = (_Float16)((a1 * c + a0 * s) * scl);
        }
      }
  }
}

// ---------------------------------------------------------------------------
// O-proj GEMM, 128(M)x64(N) tiles: grid 16x32 = 512 blocks (2/CU).
// ---------------------------------------------------------------------------
__global__ __launch_bounds__(256) void gemm_o(
    const _Float16* __restrict__ A, const _Float16* __restrict__ W,
    const float* __restrict__ bo, const float* __restrict__ res,
    float* __restrict__ out)
{
  __shared__ _Float16 As[128 * 32];
  __shared__ _Float16 Bs[64 * 32];
  const int tid = threadIdx.x, lane = tid & 63, wave = tid >> 6;
  const int quad = lane >> 4, ql = lane & 15;
  const int m0 = blockIdx.y * 128, n0 = blockIdx.x * 64;
  v4f acc[4][2];
#pragma unroll
  for (int mt = 0; mt < 4; ++mt)
#pragma unroll
    for (int nt = 0; nt < 2; ++nt) acc[mt][nt] = (v4f){0.f, 0.f, 0.f, 0.f};
  const int wm = (wave >> 1) * 64;
  const int wn = (wave & 1) * 32;
  const int srow = tid >> 2;
  const int skof = (tid & 3) * 8;
  const _Float16* Ap = A + (size_t)(m0 + srow) * DD + skof;
  const _Float16* Wp = W + (size_t)(n0 + srow) * DD + skof;
  const size_t rstep = (size_t)64 * DD;
  for (int k0 = 0; k0 < DD; k0 += 32) {
    __syncthreads();
    GLD(Ap + k0,         As + tid * 8);
    GLD(Ap + rstep + k0, As + 2048 + tid * 8);
    GLD(Wp + k0,         Bs + tid * 8);
    __syncthreads();
    v8h af[4], bf[2];
#pragma unroll
    for (int mt = 0; mt < 4; ++mt)
      af[mt] = *(const v8h*)&As[(wm + mt * 16 + ql) * 32 + quad * 8];
#pragma unroll
    for (int nt = 0; nt < 2; ++nt)
      bf[nt] = *(const v8h*)&Bs[(wn + nt * 16 + ql) * 32 + quad * 8];
#pragma unroll
    for (int mt = 0; mt < 4; ++mt)
#pragma unroll
      for (int nt = 0; nt < 2; ++nt)
        acc[mt][nt] = __builtin_amdgcn_mfma_f32_16x16x32_f16(
            af[mt], bf[nt], acc[mt][nt], 0, 0, 0);
  }
#pragma unroll
  for (int nt = 0; nt < 2; ++nt) {
    const int col = n0 + wn + nt * 16 + ql;
    const float bb = bo[col];
#pragma unroll
    for (int mt = 0; mt < 4; ++mt)
#pragma unroll
      for (int r = 0; r < 4; ++r) {
        const int row = m0 + wm + mt * 16 + quad * 4 + r;
        const size_t ix = (size_t)row * DD + col;
        out[ix] = acc[mt][nt][r] + bb + res[ix];
      }
  }
}

// ---------------------------------------------------------------------------
// Double-buffered LDS flash attention, no online-max (scores bounded).
// Round-0 __syncthreads structure, but 32 QUERIES PER WAVE (two 16-q groups):
// each K A-frag / V B-frag / amL / cs / staging byte is reused by 2 q-groups,
// halving LDS traffic per query -- the measured bottleneck (per-CU LDS flow
// was ~320 KB/tile-step vs ~100 B/cyc LDS BW, majority of wall).
// Block = 4 waves = 128 queries; grid 512 (16 qt x 32 bh) = 2 blocks/CU.
// Diagonal exception deleted (mask dot on diagonal = c^2+s^2 of identical
// f16 entries = 1 +- 2e-3, never < -0.7). am added in exp path (round-0
// style; the C-init variant serialized MFMA on ds_read and regressed).
// ---------------------------------------------------------------------------
__global__ __launch_bounds__(256, 2) void attn_db(
    const _Float16* __restrict__ Q, const _Float16* __restrict__ K,
    const _Float16* __restrict__ VT2, const unsigned* __restrict__ csh2,
    const float* __restrict__ aml2, _Float16* __restrict__ ctx)
{
  __shared__ _Float16 Kt[2][4096];   // [buf] 64 rows x 64 dims (16B-swizzled)
  __shared__ _Float16 Vt[2][4096];   // [buf] VT2 tile image (8B units j-major)
  __shared__ float amL[LL];          // am * log2e, whole row: 8 KB

  const int tid  = threadIdx.x;
  const int lane = tid & 63;
  const int wave = tid >> 6;
  const int quad = lane >> 4;
  const int ql   = lane & 15;
  const int bid  = blockIdx.x;       // 512 = 16 qt * 32 bh
  const int bh = bid & 31;           // XCD swizzle: same (b,h) -> same XCD
  const int qt = bid >> 5;
  const int h  = bh & 15;
  const int b  = bh >> 4;
  const int q0w = qt * 128 + wave * 32;   // 32 queries per wave
  const int csb = bh * LL;

  {
    const float* amb = aml2 + b * LL;
    for (int i = tid; i < LL; i += 256) amL[i] = amb[i];
  }

  // Q B-fragments for the two 16-query groups (rotary etc. pre-folded)
  v8h qf0[2], qf1[2];
  v4h bq0, bq1;
  {
    const _Float16* qp = Q + ((size_t)(b * LL + q0w + ql)) * DD + h * 64 + quad * 8;
    qf0[0] = *(const v8h*)qp;
    qf0[1] = *(const v8h*)(qp + 32);
    const v2h c2 = __builtin_bit_cast(v2h, csh2[csb + q0w + ql]);
    v4h t = (v4h){0, 0, 0, 0};
    if (quad == 0) { t[0] = c2[0]; t[1] = c2[1]; }
    bq0 = t;
  }
  {
    const _Float16* qp = Q + ((size_t)(b * LL + q0w + 16 + ql)) * DD + h * 64 + quad * 8;
    qf1[0] = *(const v8h*)qp;
    qf1[1] = *(const v8h*)(qp + 32);
    const v2h c2 = __builtin_bit_cast(v2h, csh2[csb + q0w + 16 + ql]);
    v4h t = (v4h){0, 0, 0, 0};
    if (quad == 0) { t[0] = c2[0]; t[1] = c2[1]; }
    bq1 = t;
  }
  const v4h ones = (v4h){(_Float16)1.f, (_Float16)1.f,
                         (_Float16)1.f, (_Float16)1.f};

  v4f o0[4], o1[4];
#pragma unroll
  for (int nt = 0; nt < 4; ++nt) {
    o0[nt] = (v4f){0.f, 0.f, 0.f, 0.f};
    o1[nt] = (v4f){0.f, 0.f, 0.f, 0.f};
  }
  v4f lacc0 = (v4f){0.f, 0.f, 0.f, 0.f};
  v4f lacc1 = (v4f){0.f, 0.f, 0.f, 0.f};

  const _Float16* Kb   = K + (size_t)(b * LL) * DD + h * 64;     // row stride 1024
  const _Float16* VTb2 = VT2 + (size_t)bh * 131072;              // 32 tiles x 4096
  const unsigned* csk = csh2 + csb;

  const int srow = tid >> 3;                // 0..31 K staging row
  const int kch  = (tid & 7) ^ (srow & 7);  // swizzled source 16B chunk (K only)

  // prologue: tile 0 -> buf 0; csk for tile 0 -> registers
  {
    const size_t kg = (size_t)srow * 1024 + kch * 8;
    GLD(Kb + kg,             &Kt[0][tid * 8]);
    GLD(Kb + kg + 32 * 1024, &Kt[0][2048 + tid * 8]);
    GLD(VTb2 + tid * 8,          &Vt[0][tid * 8]);
    GLD(VTb2 + 2048 + tid * 8,   &Vt[0][2048 + tid * 8]);
  }
  unsigned cs_cur[4], cs_nxt[4];
#pragma unroll
  for (int c = 0; c < 4; ++c) cs_cur[c] = csk[c * 16 + ql];
  __syncthreads();

  for (int t = 0; t < 32; ++t) {
    const int k0 = t * 64;
    const int buf = t & 1;
    if (t < 31) {
      const int k1 = k0 + 64;
      const size_t kg = (size_t)(k1 + srow) * 1024 + kch * 8;
      GLD(Kb + kg,             &Kt[buf ^ 1][tid * 8]);
      GLD(Kb + kg + 32 * 1024, &Kt[buf ^ 1][2048 + tid * 8]);
      const _Float16* vsrc = VTb2 + (size_t)(t + 1) * 4096;
      GLD(vsrc + tid * 8,        &Vt[buf ^ 1][tid * 8]);
      GLD(vsrc + 2048 + tid * 8, &Vt[buf ^ 1][2048 + tid * 8]);
#pragma unroll
      for (int c = 0; c < 4; ++c) cs_nxt[c] = csk[k1 + c * 16 + ql];
    }
    const _Float16* KtB = Kt[buf];
    const _Float16* VtB = Vt[buf];

    // --- S^T (log2 domain) + mask-dot MFMA, both q-groups sharing K frags ---
    v4f st0[4], st1[4], dd0[4], dd1[4];
#pragma unroll
    for (int c = 0; c < 4; ++c) {
      const int row = c * 16 + ql;
      const int sw = row & 7;
      v8h a0 = *(const v8h*)&KtB[row * 64 + ((quad ^ sw) << 3)];
      v8h a1 = *(const v8h*)&KtB[row * 64 + (((quad + 4) ^ sw) << 3)];
      v4f z0 = (v4f){0.f, 0.f, 0.f, 0.f};
      z0 = __builtin_amdgcn_mfma_f32_16x16x32_f16(a0, qf0[0], z0, 0, 0, 0);
      z0 = __builtin_amdgcn_mfma_f32_16x16x32_f16(a1, qf0[1], z0, 0, 0, 0);
      st0[c] = z0;
      v4f z1 = (v4f){0.f, 0.f, 0.f, 0.f};
      z1 = __builtin_amdgcn_mfma_f32_16x16x32_f16(a0, qf1[0], z1, 0, 0, 0);
      z1 = __builtin_amdgcn_mfma_f32_16x16x32_f16(a1, qf1[1], z1, 0, 0, 0);
      st1[c] = z1;
      const v2h c2 = __builtin_bit_cast(v2h, cs_cur[c]);
      v4h a = (v4h){0, 0, 0, 0};
      if (quad == 0) { a[0] = c2[0]; a[1] = c2[1]; }
      dd0[c] = __builtin_amdgcn_mfma_f32_16x16x16f16(
          a, bq0, (v4f){0.f, 0.f, 0.f, 0.f}, 0, 0, 0);
      dd1[c] = __builtin_amdgcn_mfma_f32_16x16x16f16(
          a, bq1, (v4f){0.f, 0.f, 0.f, 0.f}, 0, 0, 0);
    }

    // --- mask + P = exp2(score + am): cmp + cndmask + add + exp2 ---
    v4h pf0[4], pf1[4];
#pragma unroll
    for (int c = 0; c < 4; ++c) {
      const v4f am4 = *(const v4f*)&amL[k0 + c * 16 + quad * 4];
      float p0[4], p1[4];
#pragma unroll
      for (int r = 0; r < 4; ++r) {
        p0[r] = __builtin_amdgcn_exp2f(
            ((dd0[c][r] < -0.7f) ? NEGB : st0[c][r]) + am4[r]);
        p1[r] = __builtin_amdgcn_exp2f(
            ((dd1[c][r] < -0.7f) ? NEGB : st1[c][r]) + am4[r]);
      }
      const unsigned a01 = __builtin_bit_cast(
          unsigned, __builtin_amdgcn_cvt_pkrtz(p0[0], p0[1]));
      const unsigned a23 = __builtin_bit_cast(
          unsigned, __builtin_amdgcn_cvt_pkrtz(p0[2], p0[3]));
      pf0[c] = __builtin_bit_cast(v4h, make_uint2(a01, a23));
      const unsigned b01 = __builtin_bit_cast(
          unsigned, __builtin_amdgcn_cvt_pkrtz(p1[0], p1[1]));
      const unsigned b23 = __builtin_bit_cast(
          unsigned, __builtin_amdgcn_cvt_pkrtz(p1[2], p1[3]));
      pf1[c] = __builtin_bit_cast(v4h, make_uint2(b01, b23));
    }

    // --- PV + row-sum, V frags shared by both q-groups ---
#pragma unroll
    for (int c = 0; c < 4; ++c) {
      lacc0 = __builtin_amdgcn_mfma_f32_16x16x16f16(pf0[c], ones, lacc0, 0, 0, 0);
      lacc1 = __builtin_amdgcn_mfma_f32_16x16x16f16(pf1[c], ones, lacc1, 0, 0, 0);
#pragma unroll
      for (int nt = 0; nt < 4; ++nt) {
        const v4h vv = *(const v4h*)&VtB[((c * 4 + quad) * 64 +
                                          nt * 16 + ql) * 4];
        o0[nt] = __builtin_amdgcn_mfma_f32_16x16x16f16(pf0[c], vv, o0[nt], 0, 0, 0);
        o1[nt] = __builtin_amdgcn_mfma_f32_16x16x16f16(pf1[c], vv, o1[nt], 0, 0, 0);
      }
    }
#pragma unroll
    for (int c = 0; c < 4; ++c) cs_cur[c] = cs_nxt[c];
    __syncthreads();
  }

  // epilogue: lacc is already in O's row layout (query = g*16 + quad*4 + r)
#pragma unroll
  for (int g = 0; g < 2; ++g) {
    const v4f* op = g ? o1 : o0;
    const v4f la = g ? lacc1 : lacc0;
#pragma unroll
    for (int r = 0; r < 4; ++r) {
      const int q = q0w + g * 16 + quad * 4 + r;
      const float lr = la[r];
      const size_t ob = (size_t)(b * LL + q) * DD + h * 64 + ql;
      if (lr <= 0.f) {  // all-masked fallback (never taken with am=0)
        const _Float16* vsrc = VTb2 + (q >> 6) * 4096 +
                               ((q >> 2) & 15) * 256 + (q & 3);
#pragma unroll
        for (int nt = 0; nt < 4; ++nt)
          ctx[ob + nt * 16] = vsrc[(nt * 16 + ql) * 4];
      } else {
        const float inv = 1.f / lr;
        ctx[ob + 0]  = (_Float16)(op[0][r] * inv);
        ctx[ob + 16] = (_Float16)(op[1][r] * inv);
        ctx[ob + 32] = (_Float16)(op[2][r] * inv);
        ctx[ob + 48] = (_Float16)(op[3][r] * inv);
      }
    }
  }
}

// ---------------------------------------------------------------------------
// LayerNorm over D=1024
// ---------------------------------------------------------------------------
__global__ __launch_bounds__(256) void layernorm(
    const float* __restrict__ x, const float* __restrict__ g,
    const float* __restrict__ bta, float* __restrict__ out)
{
  __shared__ float red[8];
  const int row = blockIdx.x;
  const int tid = threadIdx.x;
  const float* xr = x + (size_t)row * DD;
  float lsum = 0.f, lsq = 0.f;
  float v[4];
#pragma unroll
  for (int i = 0; i < 4; ++i) {
    v[i] = xr[tid + i * 256];
    lsum += v[i];
    lsq += v[i] * v[i];
  }
#pragma unroll
  for (int off = 32; off > 0; off >>= 1) {
    lsum += __shfl_down(lsum, off, 64);
    lsq  += __shfl_down(lsq,  off, 64);
  }
  const int wid = tid >> 6;
  if ((tid & 63) == 0) { red[wid] = lsum; red[wid + 4] = lsq; }
  __syncthreads();
  const float tsum = red[0] + red[1] + red[2] + red[3];
  const float tsq  = red[4] + red[5] + red[6] + red[7];
  const float mean = tsum * (1.f / DD);
  const float var  = tsq * (1.f / DD) - mean * mean;
  const float inv  = rsqrtf(var + 1e-12f);
#pragma unroll
  for (int i = 0; i < 4; ++i) {
    const int c = tid + i * 256;
    out[(size_t)row * DD + c] = (v[i] - mean) * inv * g[c] + bta[c];
  }
}

// ---------------------------------------------------------------------------
extern "C" void kernel_launch(void* const* d_in, const int* in_sizes, int n_in,
                              void* d_out, int out_size, void* d_ws, size_t ws_size,
                              hipStream_t stream)
{
  const float* hs  = (const float*)d_in[0];
  const float* amk = (const float*)d_in[1];
  const float* phi = (const float*)d_in[2];
  const float* Wq  = (const float*)d_in[3];
  const float* bq  = (const float*)d_in[4];
  const float* Wk  = (const float*)d_in[5];
  const float* bk  = (const float*)d_in[6];
  const float* Wv  = (const float*)d_in[7];
  const float* bv  = (const float*)d_in[8];
  const float* Wo  = (const float*)d_in[9];
  const float* bo  = (const float*)d_in[10];
  const float* lng = (const float*)d_in[11];
  const float* lnb = (const float*)d_in[12];
  float* out = (float*)d_out;

  const size_t SZ = (size_t)BB * LL * DD;   // 4 M elements
  _Float16* hsh   = (_Float16*)d_ws;
  _Float16* qh    = hsh + SZ;
  _Float16* kh    = qh + SZ;
  _Float16* vt2   = kh + SZ;                // 4 M (V pre-tiled VT2)
  _Float16* ctxh  = vt2 + SZ;
  _Float16* wqkvh = ctxh + SZ;              // 3 M
  _Float16* woh   = wqkvh + 3 * (size_t)DD * DD;  // 1 M
  float* xb    = (float*)(woh + (size_t)DD * DD);
  unsigned* csh2 = (unsigned*)(xb + SZ);    // B*H*L packed {cos,sin} f16
  float* aml2 = (float*)(csh2 + (size_t)BB * HH * LL);  // B*L am*log2e

  cvt_all<<<8192, 256, 0, stream>>>(hs, Wq, Wk, Wv, Wo, hsh, wqkvh, woh);
  csgen<<<256, 256, 0, stream>>>(phi, amk, csh2, aml2);
  gemm_qkv<<<dim3(24, 32), 256, 0, stream>>>(hsh, wqkvh, bq, bk, bv, csh2,
                                             qh, kh, vt2);
  attn_db<<<512, 256, 0, stream>>>(qh, kh, vt2, csh2, aml2, ctxh);
  gemm_o<<<dim3(16, 32), 256, 0, stream>>>(ctxh, woh, bo, hs, xb);
  layernorm<<<BB * LL, 256, 0, stream>>>(xb, lng, lnb, out);
}